// Round 2
// baseline (351.999 us; speedup 1.0000x reference)
//
#include <hip/hip_runtime.h>
#include <math.h>

// ACT skip-RNN, H=O=4096, I=4095 (xin=[flag,x], len 4096).
// acc += 2*sigmoid(W_halt@s_new + 1.0); halts when acc >= 0.99 (step 1 for this data).
// Persistent plain-launch kernel with a software grid barrier (cooperative launch
// failed silently in R1). grid=256 blocks on 256 CUs, 4 waves/block -> always
// co-resident (1024 waves << 8192-wave capacity), so the spin barrier is safe.

#define H      4096
#define GRID   256
#define TPB    256
#define NWAVE  4
#define RPB    (H / GRID)    // 16 rows per block
#define RPW    (RPB / NWAVE) // 4 rows per wave
#define NMAX   16
#define THRESH 0.99f         // 1.0 - EPS

// ws float layout: [0]=cnt [1]=gen [2..2+NMAX)=hdot[t] | [32..32+H)=sb0 | [32+H..32+2H)=sb1
// First 128 bytes zeroed via hipMemsetAsync before launch.

__device__ __forceinline__ float wave_reduce(float a) {
    #pragma unroll
    for (int off = 32; off > 0; off >>= 1) a += __shfl_down(a, off);
    return a;
}

__device__ __forceinline__ void grid_barrier(int* cnt, int* gen) {
    __syncthreads();
    if (threadIdx.x == 0) {
        __threadfence();  // release: publish this block's global writes (agent scope)
        int g = __hip_atomic_load(gen, __ATOMIC_RELAXED, __HIP_MEMORY_SCOPE_AGENT);
        int prev = __hip_atomic_fetch_add(cnt, 1, __ATOMIC_ACQ_REL, __HIP_MEMORY_SCOPE_AGENT);
        if (prev == GRID - 1) {
            __hip_atomic_store(cnt, 0, __ATOMIC_RELAXED, __HIP_MEMORY_SCOPE_AGENT);
            __hip_atomic_fetch_add(gen, 1, __ATOMIC_RELEASE, __HIP_MEMORY_SCOPE_AGENT);
        } else {
            while (__hip_atomic_load(gen, __ATOMIC_ACQUIRE, __HIP_MEMORY_SCOPE_AGENT) == g)
                __builtin_amdgcn_s_sleep(8);
        }
        __threadfence();  // acquire: invalidate L1/L2 so post-barrier reads are fresh
    }
    __syncthreads();
}

__global__ void act_skip_rnn(
    const float* __restrict__ x,      const float* __restrict__ s0,
    const float* __restrict__ y0,     const float* __restrict__ h0,
    const float* __restrict__ W_ih,   const float* __restrict__ b_ih,
    const float* __restrict__ W_hh,   const float* __restrict__ b_hh,
    const float* __restrict__ W_halt, const float* __restrict__ b_halt,
    const float* __restrict__ W_out,  const float* __restrict__ b_out,
    float* __restrict__ out, float* ws)
{
    int*   cnt  = (int*)ws;
    int*   gen  = (int*)ws + 1;
    float* hdot = ws + 2;
    float* sb0  = ws + 32;
    float* sb1  = ws + 32 + H;

    const int tid  = threadIdx.x;
    const int bid  = blockIdx.x;
    const int wave = tid >> 6;
    const int lane = tid & 63;

    __shared__ float xl[H];   // xin (flag slot = 0; flag handled via W_ih col 0 at t==0)
    __shared__ float sl[H];   // current s

    // stage xin into LDS (per-block; x is tiny vs 512KB of weights per step)
    if (tid == 0) xl[0] = 0.f;
    for (int i = tid; i < H - 1; i += TPB) xl[i + 1] = x[i];

    const float h0v = h0[0];
    const float h0b = (h0v >= THRESH) ? 1.f : 0.f;   // binarize(h0)
    const float bh  = b_halt[0];

    float  acc      = h0v;
    float  last_acc = 0.f;
    int    ponder   = 0;
    bool   halted   = false;
    float* slast    = sb0;

    if (h0b == 0.f) {
        for (int t = 0; t < NMAX; ++t) {
            const float* scur = (t == 0) ? s0 : ((t & 1) ? sb0 : sb1);
            float*       snew = (t & 1) ? sb1 : sb0;

            // stage current s into LDS
            __syncthreads();
            for (int i = tid; i < H / 4; i += TPB)
                ((float4*)sl)[i] = ((const float4*)scur)[i];
            __syncthreads();

            // Phase A: this block's 16 rows of s_new = tanh(W_ih@xin + W_hh@s + b)
            float hpart = 0.f;
            for (int r = 0; r < RPW; ++r) {
                const int row = bid * RPB + r * NWAVE + wave;
                const float4* wih = (const float4*)(W_ih + (size_t)row * H);
                const float4* whh = (const float4*)(W_hh + (size_t)row * H);
                float a = 0.f;
                #pragma unroll
                for (int k = 0; k < 16; ++k) {
                    const int idx = lane + (k << 6);   // lane-contiguous float4
                    float4 wa = wih[idx], va = ((const float4*)xl)[idx];
                    float4 wb = whh[idx], vb = ((const float4*)sl)[idx];
                    a += wa.x*va.x + wa.y*va.y + wa.z*va.z + wa.w*va.w
                       + wb.x*vb.x + wb.y*vb.y + wb.z*vb.z + wb.w*vb.w;
                }
                a = wave_reduce(a);
                if (lane == 0) {
                    float z = a + b_ih[row] + b_hh[row];
                    if (t == 0) z += W_ih[(size_t)row * H];  // xin[0]=1 on first step
                    float sv = tanhf(z);
                    snew[row] = sv;
                    hpart += W_halt[row] * sv;   // this block's halt-dot contribution
                }
            }
            if (lane == 0) atomicAdd(&hdot[t], hpart);

            grid_barrier(cnt, gen);

            // uniform halt update (identical in every block; no divergent barriers)
            float hd = ((volatile float*)hdot)[t];
            float sg = 1.f / (1.f + expf(-(hd + bh)));
            acc += 2.f * sg;
            if (acc >= THRESH) { halted = true; last_acc = acc; slast = snew; break; }
            ponder++;
        }
    }

    // ---- epilogue ----
    if (h0b != 0.f) {
        for (int i = bid * TPB + tid; i < H; i += GRID * TPB) {
            out[i]     = y0[i];
            out[H + i] = s0[i];
        }
        if (bid == 0 && tid == 0) { out[2*H] = 0.f; out[2*H + 1] = h0v - 1.f; }
        return;
    }
    if (!halted) {  // ran all NMAX steps without halting: y_sel = s_sel = 0
        for (int i = bid * TPB + tid; i < H; i += GRID * TPB) {
            out[i]     = 0.f;
            out[H + i] = 0.f;
        }
        if (bid == 0 && tid == 0) { out[2*H] = (float)ponder; out[2*H + 1] = -1.f; }
        return;
    }

    // halted: y = W_out @ s_halt + b_out
    __syncthreads();
    for (int i = tid; i < H / 4; i += TPB)
        ((float4*)sl)[i] = ((const float4*)slast)[i];
    __syncthreads();

    for (int r = 0; r < RPW; ++r) {
        const int row = bid * RPB + r * NWAVE + wave;
        const float4* wo = (const float4*)(W_out + (size_t)row * H);
        float a = 0.f;
        #pragma unroll
        for (int k = 0; k < 16; ++k) {
            const int idx = lane + (k << 6);
            float4 w4 = wo[idx], s4 = ((const float4*)sl)[idx];
            a += w4.x*s4.x + w4.y*s4.y + w4.z*s4.z + w4.w*s4.w;
        }
        a = wave_reduce(a);
        if (lane == 0) {
            out[row]     = a + b_out[row];
            out[H + row] = sl[row];
        }
    }
    if (bid == 0 && tid == 0) {
        out[2*H]     = (float)ponder;
        out[2*H + 1] = last_acc - 1.f;
    }
}

extern "C" void kernel_launch(void* const* d_in, const int* in_sizes, int n_in,
                              void* d_out, int out_size, void* d_ws, size_t ws_size,
                              hipStream_t stream) {
    const float* x      = (const float*)d_in[0];
    const float* s0     = (const float*)d_in[1];
    const float* y0     = (const float*)d_in[2];
    const float* h0     = (const float*)d_in[3];
    const float* W_ih   = (const float*)d_in[4];
    const float* b_ih   = (const float*)d_in[5];
    const float* W_hh   = (const float*)d_in[6];
    const float* b_hh   = (const float*)d_in[7];
    const float* W_halt = (const float*)d_in[8];
    const float* b_halt = (const float*)d_in[9];
    const float* W_out  = (const float*)d_in[10];
    const float* b_out  = (const float*)d_in[11];
    float* out = (float*)d_out;
    float* ws  = (float*)d_ws;   // needs (32 + 2*4096)*4 B ≈ 33 KB

    // zero barrier counters + hdot slots (ws is poisoned 0xAA before every call)
    hipMemsetAsync(ws, 0, 128, stream);

    act_skip_rnn<<<dim3(GRID), dim3(TPB), 0, stream>>>(
        x, s0, y0, h0, W_ih, b_ih, W_hh, b_hh,
        W_halt, b_halt, W_out, b_out, out, ws);
}